// Round 9
// baseline (6598.465 us; speedup 1.0000x reference)
//
#include <hip/hip_runtime.h>
#include <math.h>

// Model: S=1024, V=32000, H=1024. Attention dead code => context = sum enc_h.
//
// Round-9 structure (serial, proven components + MFMA logits):
//   memsets: amax+zerovec zero; enc_out/dec_h NaN sentinel
//   g_both    : G_enc (bias enc_b) and G_dec (no bias) GEMMs, one launch
//   lstm_seq  : encoder (round-5 proven), -> enc_out, c0, ctx
//   ctx_bias_k: ctxb = dec_b + dec_Wih[:,H:] @ ctx
//   dec_lstm  : decoder (round-8 proven body: G_dec + per-thread gctx)
//   logits_mfma: bf16x3 split-precision MFMA GEMM (error ~1e-4, fp32-class)
//                + bias + store + fused packed-key argmax (atomicMax)
//   idx_final : decode argmax keys -> d_out[S*V..]

#define S_LEN 1024
#define HDIM  1024
#define VDIM  32000

typedef float f4 __attribute__((ext_vector_type(4)));
typedef float f32x4 __attribute__((ext_vector_type(4)));
typedef short short8 __attribute__((ext_vector_type(8)));

__device__ __forceinline__ void agent_storef(float* p, float v) {
    __hip_atomic_store(p, v, __ATOMIC_RELAXED, __HIP_MEMORY_SCOPE_AGENT);
}
__device__ __forceinline__ float sigmoidf_(float x) {
    return 1.0f / (1.0f + expf(-x));
}
__device__ __forceinline__ void llc_load_4x4(const float* p, f4& a, f4& b,
                                             f4& c, f4& d) {
    asm volatile(
        "global_load_dwordx4 %0, %4, off sc0 sc1\n\t"
        "global_load_dwordx4 %1, %4, off offset:1024 sc0 sc1\n\t"
        "global_load_dwordx4 %2, %4, off offset:2048 sc0 sc1\n\t"
        "global_load_dwordx4 %3, %4, off offset:3072 sc0 sc1\n\t"
        "s_waitcnt vmcnt(0)"
        : "=&v"(a), "=&v"(b), "=&v"(c), "=&v"(d)
        : "v"(p) : "memory");
}
__device__ __forceinline__ bool any_nan16(f4 a, f4 b, f4 c, f4 d) {
    float s0 = (a.x + a.y) + (a.z + a.w);
    float s1 = (b.x + b.y) + (b.z + b.w);
    float s2 = (c.x + c.y) + (c.z + c.w);
    float s3 = (d.x + d.y) + (d.z + d.w);
    float s  = (s0 + s1) + (s2 + s3);
    return s != s;
}
__device__ __forceinline__ int swz(int s) {
    return (s & ~7) | ((s ^ (s >> 3)) & 7);
}
// RNE split: x = hi + lo with |lo| <= 2^-9 |x|, both bf16.
__device__ __forceinline__ void split_bf16(float x, unsigned short& h,
                                           unsigned short& l) {
    unsigned u = __float_as_uint(x);
    unsigned hr = (u + 0x7FFFu + ((u >> 16) & 1u)) >> 16;
    h = (unsigned short)hr;
    float hf = __uint_as_float(hr << 16);
    float r = x - hf;
    unsigned v = __float_as_uint(r);
    l = (unsigned short)((v + 0x7FFFu + ((v >> 16) & 1u)) >> 16);
}

// ---------------------------------------------------------------------------
// Input GEMMs (round-8 proven): 256-thread 128x128 tile.
// MODE 1: A = embed[gidx[m]], +bias; MODE 2: A = relu(embed[gidx[m-1]]), row0=0
// ---------------------------------------------------------------------------
template<int MODE>
__device__ void gemm_body(const float* __restrict__ B, int ldb,
                          const float* __restrict__ bias,
                          float* __restrict__ C, int ldc,
                          const float* __restrict__ embed,
                          const int* __restrict__ gidx,
                          int m0, int n0, int K)
{
    __shared__ float As[16][128];
    __shared__ float Bs[16][128];
    const int tid = threadIdx.x;

    float acc[8][8];
#pragma unroll
    for (int r = 0; r < 8; ++r)
#pragma unroll
        for (int c = 0; c < 8; ++c) acc[r][c] = 0.0f;

    const int ty = tid >> 4;
    const int tx = tid & 15;

    for (int k0 = 0; k0 < K; k0 += 16) {
#pragma unroll
        for (int q = 0; q < 2; ++q) {
            int id = tid * 2 + q;
            int m  = id >> 2;
            int c4 = (id & 3) * 4;
            float4 v;
            if (MODE == 1) {
                int row = gidx[m0 + m];
                v = *(const float4*)(embed + (size_t)row * HDIM + k0 + c4);
            } else {
                int mg = m0 + m;
                if (mg == 0) {
                    v = make_float4(0.f, 0.f, 0.f, 0.f);
                } else {
                    int row = gidx[mg - 1];
                    v = *(const float4*)(embed + (size_t)row * HDIM + k0 + c4);
                    v.x = fmaxf(v.x, 0.f); v.y = fmaxf(v.y, 0.f);
                    v.z = fmaxf(v.z, 0.f); v.w = fmaxf(v.w, 0.f);
                }
            }
            As[c4 + 0][m] = v.x; As[c4 + 1][m] = v.y;
            As[c4 + 2][m] = v.z; As[c4 + 3][m] = v.w;
        }
#pragma unroll
        for (int q = 0; q < 2; ++q) {
            int id = tid * 2 + q;
            int n  = id >> 2;
            int c4 = (id & 3) * 4;
            float4 v = *(const float4*)(B + (size_t)(n0 + n) * ldb + k0 + c4);
            Bs[c4 + 0][n] = v.x; Bs[c4 + 1][n] = v.y;
            Bs[c4 + 2][n] = v.z; Bs[c4 + 3][n] = v.w;
        }
        __syncthreads();
#pragma unroll
        for (int k = 0; k < 16; ++k) {
            float4 a0 = *(const float4*)&As[k][ty * 8];
            float4 a1 = *(const float4*)&As[k][ty * 8 + 4];
            float4 b0 = *(const float4*)&Bs[k][tx * 8];
            float4 b1 = *(const float4*)&Bs[k][tx * 8 + 4];
            float av[8] = {a0.x,a0.y,a0.z,a0.w,a1.x,a1.y,a1.z,a1.w};
            float bv[8] = {b0.x,b0.y,b0.z,b0.w,b1.x,b1.y,b1.z,b1.w};
#pragma unroll
            for (int r = 0; r < 8; ++r)
#pragma unroll
                for (int c = 0; c < 8; ++c)
                    acc[r][c] = fmaf(av[r], bv[c], acc[r][c]);
        }
        __syncthreads();
    }

    const int mbase = m0 + ty * 8;
    const int nbase = n0 + tx * 8;
#pragma unroll
    for (int r = 0; r < 8; ++r) {
        float4 o0, o1;
        float b0 = (MODE == 2) ? 0.f : bias[nbase + 0];
        float b1 = (MODE == 2) ? 0.f : bias[nbase + 1];
        float b2 = (MODE == 2) ? 0.f : bias[nbase + 2];
        float b3 = (MODE == 2) ? 0.f : bias[nbase + 3];
        float b4 = (MODE == 2) ? 0.f : bias[nbase + 4];
        float b5 = (MODE == 2) ? 0.f : bias[nbase + 5];
        float b6 = (MODE == 2) ? 0.f : bias[nbase + 6];
        float b7 = (MODE == 2) ? 0.f : bias[nbase + 7];
        o0.x = acc[r][0] + b0; o0.y = acc[r][1] + b1;
        o0.z = acc[r][2] + b2; o0.w = acc[r][3] + b3;
        o1.x = acc[r][4] + b4; o1.y = acc[r][5] + b5;
        o1.z = acc[r][6] + b6; o1.w = acc[r][7] + b7;
        *(float4*)(C + (size_t)(mbase + r) * ldc + nbase)     = o0;
        *(float4*)(C + (size_t)(mbase + r) * ldc + nbase + 4) = o1;
    }
}

__global__ __launch_bounds__(256)
void g_both(const float* __restrict__ embed,
            const int* __restrict__ input_seq,
            const int* __restrict__ gold_seq,
            const float* __restrict__ enc_Wih,
            const float* __restrict__ enc_b,
            const float* __restrict__ dec_Wih,
            float* __restrict__ G_enc,
            float* __restrict__ G_dec)
{
    const int bx = blockIdx.x, by = blockIdx.y;
    if (by < 8)
        gemm_body<1>(enc_Wih, HDIM, enc_b, G_enc, 4 * HDIM,
                     embed, input_seq, by * 128, bx * 128, HDIM);
    else
        gemm_body<2>(dec_Wih, 2 * HDIM, nullptr, G_dec, 4 * HDIM,
                     embed, gold_seq, (by - 8) * 128, bx * 128, HDIM);
}

// ---------------------------------------------------------------------------
// LSTM (round-5/8 proven body). GCTX=0: encoder; GCTX=1: decoder (+gctx).
// ---------------------------------------------------------------------------
template<int GCTX>
__device__ void lstm_body(const float* __restrict__ Whh,
                          const float* __restrict__ G,
                          const float* __restrict__ gctx_vec,
                          const float* __restrict__ h_init,
                          const float* __restrict__ c_init,
                          float* __restrict__ h_out,
                          float* __restrict__ c_fin,
                          float* __restrict__ csum_out,
                          int slen)
{
    __shared__ f4 hbuf[256];
    const int tid = threadIdx.x;
    const int g   = blockIdx.x;
    const int wv  = tid >> 6;
    const int lg  = tid & 63;
    const int j   = g * 8 + wv;

    f4 W[4][4];
#pragma unroll
    for (int q = 0; q < 4; ++q)
#pragma unroll
        for (int i = 0; i < 4; ++i)
            W[q][i] = *(const f4*)(Whh + (size_t)(j + q * HDIM) * HDIM
                                   + 4 * lg + 256 * i);

    float c = 0.0f, csum = 0.0f;
    if (lg == 0) c = c_init[j];

    float gctx = 0.0f;
    if (GCTX) gctx = gctx_vec[(size_t)(lg & 3) * HDIM + j];

    float gnow = G[(size_t)(lg & 3) * HDIM + j] + gctx;

    for (int t = 0; t < slen; ++t) {
#pragma unroll
        for (int q = 0; q < 4; ++q)
#pragma unroll
            for (int i = 0; i < 4; ++i)
                asm volatile("" : "+v"(W[q][i]));

        const float* hp = (t == 0) ? h_init : (h_out + (size_t)(t - 1) * HDIM);

        if (wv == 0) {
            f4 a, b, cc, d;
            const float* p = hp + 4 * lg;
            for (;;) {
                llc_load_4x4(p, a, b, cc, d);
                if (!__any(any_nan16(a, b, cc, d))) break;
                __builtin_amdgcn_s_sleep(1);
            }
            hbuf[swz(lg)]       = a;
            hbuf[swz(64 + lg)]  = b;
            hbuf[swz(128 + lg)] = cc;
            hbuf[swz(192 + lg)] = d;
        }
        __syncthreads();

        int tn = (t + 1 < slen) ? (t + 1) : t;
        float gnext = G[(size_t)tn * (4 * HDIM) + (lg & 3) * HDIM + j] + gctx;

        f4 h0 = hbuf[swz(lg)];
        f4 h1 = hbuf[swz(64 + lg)];
        f4 h2 = hbuf[swz(128 + lg)];
        f4 h3 = hbuf[swz(192 + lg)];
        float p0 = 0.f, p1 = 0.f, p2 = 0.f, p3 = 0.f;
        f4 hv;
#pragma unroll
        for (int i = 0; i < 4; ++i) {
            hv = (i == 0) ? h0 : (i == 1) ? h1 : (i == 2) ? h2 : h3;
            p0 = fmaf(W[0][i].x, hv.x, fmaf(W[0][i].y, hv.y,
                 fmaf(W[0][i].z, hv.z, fmaf(W[0][i].w, hv.w, p0))));
            p1 = fmaf(W[1][i].x, hv.x, fmaf(W[1][i].y, hv.y,
                 fmaf(W[1][i].z, hv.z, fmaf(W[1][i].w, hv.w, p1))));
            p2 = fmaf(W[2][i].x, hv.x, fmaf(W[2][i].y, hv.y,
                 fmaf(W[2][i].z, hv.z, fmaf(W[2][i].w, hv.w, p2))));
            p3 = fmaf(W[3][i].x, hv.x, fmaf(W[3][i].y, hv.y,
                 fmaf(W[3][i].z, hv.z, fmaf(W[3][i].w, hv.w, p3))));
        }

        float t01 = __shfl_xor((lg & 1) ? p0 : p1, 1);
        float s01 = ((lg & 1) ? p1 : p0) + t01;
        float t23 = __shfl_xor((lg & 1) ? p2 : p3, 1);
        float s23 = ((lg & 1) ? p3 : p2) + t23;
        float tq  = __shfl_xor((lg & 2) ? s01 : s23, 2);
        float s   = ((lg & 2) ? s23 : s01) + tq;
        s += __shfl_xor(s, 4);
        s += __shfl_xor(s, 8);
        s += __shfl_xor(s, 16);
        s += __shfl_xor(s, 32);

        float pre = s + gnow;
        float act = ((lg & 3) == 2) ? tanhf(pre) : sigmoidf_(pre);
        float a1 = __shfl(act, 1);
        float a2 = __shfl(act, 2);
        float a3 = __shfl(act, 3);

        if (lg == 0) {
            c = a1 * c + act * a2;
            float h = a3 * tanhf(c);
            csum += h;
            agent_storef(h_out + (size_t)t * HDIM + j, h);
        }
        gnow = gnext;
        __syncthreads();
    }

    if (lg == 0) {
        if (c_fin)    c_fin[j]    = c;
        if (csum_out) csum_out[j] = csum;
    }
}

__global__ __launch_bounds__(512, 2)
void lstm_seq(const float* __restrict__ Whh, const float* __restrict__ G,
              const float* __restrict__ h_init, const float* __restrict__ c_init,
              float* __restrict__ h_out, float* __restrict__ c_fin,
              float* __restrict__ csum_out, int slen)
{
    lstm_body<0>(Whh, G, nullptr, h_init, c_init, h_out, c_fin, csum_out, slen);
}

__global__ __launch_bounds__(512, 2)
void dec_lstm(const float* __restrict__ Whh, const float* __restrict__ G,
              const float* __restrict__ ctxb, const float* __restrict__ h_init,
              const float* __restrict__ c_init, float* __restrict__ h_out,
              int slen)
{
    lstm_body<1>(Whh, G, ctxb, h_init, c_init, h_out, nullptr, nullptr, slen);
}

// ctx_bias[r] = dec_b[r] + dot(dec_Wih[r, H:2H], context)
__global__ __launch_bounds__(256)
void ctx_bias_k(const float* __restrict__ dec_Wih,
                const float* __restrict__ dec_b,
                const float* __restrict__ ctx,
                float* __restrict__ out)
{
    const int wv = threadIdx.x >> 6;
    const int lane = threadIdx.x & 63;
    const int r = blockIdx.x * 4 + wv;
    const float* wr = dec_Wih + (size_t)r * (2 * HDIM) + HDIM;
    float s = 0.f;
    for (int k = lane; k < HDIM; k += 64) s += wr[k] * ctx[k];
#pragma unroll
    for (int off = 32; off > 0; off >>= 1) s += __shfl_xor(s, off);
    if (lane == 0) out[r] = s + dec_b[r];
}

// ---------------------------------------------------------------------------
// logits_mfma: C(1024,32000) = A(1024,1024) @ B(32000,1024)^T + out_b,
// bf16x3 split-precision (ah*bh + ah*bl + al*bh, fp32 MFMA accum),
// fused per-row argmax via packed u64 keys + atomicMax.
// Grid (250, 8), 256 threads (4 waves). Tile 128m x 128n, K-chunk 32.
// Wave w: m-block (w>>1)*64, n-block (w&1)*64; 4x4 frags of 16x16.
// MFMA 16x16x32 bf16: A lane l: row=l&15, k=(l>>4)*8+e; B lane l: col=l&15,
// k=(l>>4)*8+e; D lane l: col=l&15, row=(l>>4)*4+reg  [C/D HW-verified].
// ---------------------------------------------------------------------------
#define LSTR 40   // LDS row stride in ushorts (bank-spread)

__global__ __launch_bounds__(256, 1)
void logits_mfma(const float* __restrict__ Amat,   // dec_h (S,H)
                 const float* __restrict__ Bmat,   // out_w (V,H)
                 const float* __restrict__ bias,   // out_b (V)
                 float* __restrict__ C,            // (S,V)
                 unsigned long long* __restrict__ amax)
{
    __shared__ unsigned short Ah[128][LSTR], Al[128][LSTR];
    __shared__ unsigned short Bh[128][LSTR], Bl[128][LSTR];

    const int tid = threadIdx.x;
    const int l   = tid & 63;
    const int w   = tid >> 6;
    const int n0  = blockIdx.x * 128;
    const int m0  = blockIdx.y * 128;
    const int mb  = (w >> 1) * 64;
    const int nb  = (w & 1) * 64;

    f32x4 acc[4][4];
#pragma unroll
    for (int i = 0; i < 4; ++i)
#pragma unroll
        for (int j = 0; j < 4; ++j) acc[i][j] = (f32x4){0.f, 0.f, 0.f, 0.f};

    for (int k0 = 0; k0 < HDIM; k0 += 32) {
        // stage A/B chunk (128 rows x 32 k), split into bf16 hi/lo
#pragma unroll
        for (int q = 0; q < 4; ++q) {
            int id  = q * 256 + tid;      // 0..1023
            int row = id >> 3;            // 0..127
            int kq  = (id & 7) * 4;       // 0,4,..28
            float4 av = *(const float4*)(Amat + (size_t)(m0 + row) * HDIM
                                         + k0 + kq);
            float4 bv = *(const float4*)(Bmat + (size_t)(n0 + row) * HDIM
                                         + k0 + kq);
            unsigned short h0,h1,h2,h3, l0,l1,l2,l3;
            split_bf16(av.x, h0, l0); split_bf16(av.y, h1, l1);
            split_bf16(av.z, h2, l2); split_bf16(av.w, h3, l3);
            Ah[row][kq+0]=h0; Ah[row][kq+1]=h1; Ah[row][kq+2]=h2; Ah[row][kq+3]=h3;
            Al[row][kq+0]=l0; Al[row][kq+1]=l1; Al[row][kq+2]=l2; Al[row][kq+3]=l3;
            split_bf16(bv.x, h0, l0); split_bf16(bv.y, h1, l1);
            split_bf16(bv.z, h2, l2); split_bf16(bv.w, h3, l3);
            Bh[row][kq+0]=h0; Bh[row][kq+1]=h1; Bh[row][kq+2]=h2; Bh[row][kq+3]=h3;
            Bl[row][kq+0]=l0; Bl[row][kq+1]=l1; Bl[row][kq+2]=l2; Bl[row][kq+3]=l3;
        }
        __syncthreads();

        const int kb = (l >> 4) * 8;
        short8 a_hi[4], a_lo[4], b_hi[4], b_lo[4];
#pragma unroll
        for (int i = 0; i < 4; ++i) {
            int ra = mb + i * 16 + (l & 15);
            int rb = nb + i * 16 + (l & 15);
            a_hi[i] = *(const short8*)&Ah[ra][kb];
            a_lo[i] = *(const short8*)&Al[ra][kb];
            b_hi[i] = *(const short8*)&Bh[rb][kb];
            b_lo[i] = *(const short8*)&Bl[rb][kb];
        }
#pragma unroll
        for (int i = 0; i < 4; ++i)
#pragma unroll
            for (int j = 0; j < 4; ++j) {
                acc[i][j] = __builtin_amdgcn_mfma_f32_16x16x32_bf16(
                    a_hi[i], b_hi[j], acc[i][j], 0, 0, 0);
                acc[i][j] = __builtin_amdgcn_mfma_f32_16x16x32_bf16(
                    a_hi[i], b_lo[j], acc[i][j], 0, 0, 0);
                acc[i][j] = __builtin_amdgcn_mfma_f32_16x16x32_bf16(
                    a_lo[i], b_hi[j], acc[i][j], 0, 0, 0);
            }
        __syncthreads();
    }

    // epilogue: bias, store, fused argmax
#pragma unroll
    for (int i = 0; i < 4; ++i) {
        const int mrow = m0 + mb + i * 16 + ((l >> 4) << 2);
        unsigned long long key[4] = {0ull, 0ull, 0ull, 0ull};
#pragma unroll
        for (int j = 0; j < 4; ++j) {
            int n = n0 + nb + j * 16 + (l & 15);
            float bv = bias[n];
            f32x4 o = acc[i][j];
#pragma unroll
            for (int r = 0; r < 4; ++r) {
                float val = o[r] + bv;
                C[(size_t)(mrow + r) * VDIM + n] = val;
                unsigned um = __float_as_uint(val);
                um = (um & 0x80000000u) ? ~um : (um | 0x80000000u);
                unsigned long long k2 = ((unsigned long long)um << 32)
                    | (unsigned long long)(0xFFFFFFFFu - (unsigned)n);
                if (k2 > key[r]) key[r] = k2;
            }
        }
#pragma unroll
        for (int r = 0; r < 4; ++r) {
#pragma unroll
            for (int off = 1; off < 16; off <<= 1) {
                unsigned long long other = __shfl_xor(key[r], off);
                if (other > key[r]) key[r] = other;
            }
            if ((l & 15) == 0)
                atomicMax(&amax[mrow + r], key[r]);
        }
    }
}

// decode argmax keys -> float indices
__global__ __launch_bounds__(256)
void idx_final(const unsigned long long* __restrict__ amax,
               float* __restrict__ out_idx)
{
    int i = blockIdx.x * 256 + threadIdx.x;
    if (i < S_LEN) {
        unsigned col = 0xFFFFFFFFu - (unsigned)(amax[i] & 0xFFFFFFFFull);
        out_idx[i] = (float)col;
    }
}

extern "C" void kernel_launch(void* const* d_in, const int* in_sizes, int n_in,
                              void* d_out, int out_size, void* d_ws, size_t ws_size,
                              hipStream_t stream)
{
    (void)in_sizes; (void)n_in; (void)out_size; (void)ws_size;

    const int*   input_seq = (const int*)d_in[0];
    const int*   gold_seq  = (const int*)d_in[1];
    const float* embed     = (const float*)d_in[2];
    const float* enc_Wih   = (const float*)d_in[3];
    const float* enc_Whh   = (const float*)d_in[4];
    const float* enc_b     = (const float*)d_in[5];
    const float* dec_Wih   = (const float*)d_in[6];
    const float* dec_Whh   = (const float*)d_in[7];
    const float* dec_b     = (const float*)d_in[8];
    // d_in[9..14]: attention params — dead code
    const float* out_w     = (const float*)d_in[15];
    const float* out_b     = (const float*)d_in[16];

    float* out = (float*)d_out;
    float* G_enc = out;                 // dead before logits overwrite (serial)
    float* G_dec = out + 4194304;       // dead before logits overwrite (serial)

    // workspace
    char* wsb = (char*)d_ws;
    unsigned long long* amax = (unsigned long long*)wsb;   // 8 KB
    float* zerovec = (float*)(wsb + 8192);                 // 1024 f
    float* c0      = zerovec + 1024;
    float* ctx     = c0 + 1024;
    float* ctxb    = ctx + 1024;                           // 4096 f
    float* enc_out = ctxb + 4096;                          // S*H
    float* dec_h   = enc_out + 1048576;                    // S*H

    hipMemsetAsync(d_ws, 0, 12288, stream);                // amax + zerovec
    hipMemsetAsync(enc_out, 0xFF, (size_t)S_LEN * HDIM * 4, stream);
    hipMemsetAsync(dec_h,   0xFF, (size_t)S_LEN * HDIM * 4, stream);

    // both input GEMMs, one launch
    g_both<<<dim3(32, 16), 256, 0, stream>>>(
        embed, input_seq, gold_seq, enc_Wih, enc_b, dec_Wih, G_enc, G_dec);

    // encoder
    lstm_seq<<<128, 512, 0, stream>>>(
        enc_Whh, G_enc, zerovec, zerovec, enc_out, c0, ctx, S_LEN);

    // ctxb = dec_b + dec_Wih[:,H:] @ ctx
    ctx_bias_k<<<1024, 256, 0, stream>>>(dec_Wih, dec_b, ctx, ctxb);

    // decoder
    dec_lstm<<<128, 512, 0, stream>>>(
        dec_Whh, G_dec, ctxb, enc_out + (size_t)(S_LEN - 1) * HDIM, c0,
        dec_h, S_LEN);

    // logits (bf16x3 MFMA) + fused argmax
    logits_mfma<<<dim3(VDIM / 128, S_LEN / 128), 256, 0, stream>>>(
        dec_h, out_w, out_b, out, amax);

    // idxs -> d_out[S*V : S*V + S)
    idx_final<<<4, 256, 0, stream>>>(amax, out + (size_t)S_LEN * VDIM);
}

// Round 10
// 5893.319 us; speedup vs baseline: 1.1197x; 1.1197x over previous
//
#include <hip/hip_runtime.h>
#include <math.h>

// Model: S=1024, V=32000, H=1024. Attention dead code => context = sum enc_h.
//
// Round-10 structure (serial, proven components):
//   memsets: amax+zerovec zero; enc_out/dec_h NaN sentinel
//   g_both    : G_enc (bias enc_b) and G_dec (no bias) GEMMs, one launch
//   lstm_seq  : encoder (round-5 body + 2-step G prefetch ring)
//   ctx_bias_k: ctxb = dec_b + dec_Wih[:,H:] @ ctx
//   dec_lstm  : decoder (same body, G_dec + per-thread gctx)
//   logits_mfma: bf16x3 MFMA GEMM v2 (256m x 128n tiles, short4 LDS stores)
//                + bias + store + fused packed-key argmax (atomicMax)
//   idx_final : decode argmax keys -> d_out[S*V..]
//
// Round-10 deltas vs round 9:
//  (a) LSTM G loads: round 9 showed dec_lstm +870us with FETCH +16MB==|G_dec|
//      (G evicted from LLC by then; compiler sinks the load to its use at
//      VGPR-min liveness => ~900cy exposed/step). Fix: unroll recurrence by
//      2; issue BOTH t+2/t+3 G loads via raw asm at the top (no waitcnt),
//      s_waitcnt vmcnt(0)+sched_barrier(0) only after two full steps.
//  (b) logits: 256-row m-tiles (B split/read 4x not 8x), short4 LDS stores.

#define S_LEN 1024
#define HDIM  1024
#define VDIM  32000

typedef float f4 __attribute__((ext_vector_type(4)));
typedef float f32x4 __attribute__((ext_vector_type(4)));
typedef short short8 __attribute__((ext_vector_type(8)));
typedef short sh4 __attribute__((ext_vector_type(4)));

__device__ __forceinline__ void agent_storef(float* p, float v) {
    __hip_atomic_store(p, v, __ATOMIC_RELAXED, __HIP_MEMORY_SCOPE_AGENT);
}
__device__ __forceinline__ float sigmoidf_(float x) {
    return 1.0f / (1.0f + expf(-x));
}
__device__ __forceinline__ void llc_load_4x4(const float* p, f4& a, f4& b,
                                             f4& c, f4& d) {
    asm volatile(
        "global_load_dwordx4 %0, %4, off sc0 sc1\n\t"
        "global_load_dwordx4 %1, %4, off offset:1024 sc0 sc1\n\t"
        "global_load_dwordx4 %2, %4, off offset:2048 sc0 sc1\n\t"
        "global_load_dwordx4 %3, %4, off offset:3072 sc0 sc1\n\t"
        "s_waitcnt vmcnt(0)"
        : "=&v"(a), "=&v"(b), "=&v"(c), "=&v"(d)
        : "v"(p) : "memory");
}
__device__ __forceinline__ bool any_nan16(f4 a, f4 b, f4 c, f4 d) {
    float s0 = (a.x + a.y) + (a.z + a.w);
    float s1 = (b.x + b.y) + (b.z + b.w);
    float s2 = (c.x + c.y) + (c.z + c.w);
    float s3 = (d.x + d.y) + (d.z + d.w);
    float s  = (s0 + s1) + (s2 + s3);
    return s != s;
}
__device__ __forceinline__ int swz(int s) {
    return (s & ~7) | ((s ^ (s >> 3)) & 7);
}
// RNE split: x = hi + lo with |lo| <= 2^-9 |x|, both bf16.
__device__ __forceinline__ void split_bf16(float x, unsigned short& h,
                                           unsigned short& l) {
    unsigned u = __float_as_uint(x);
    unsigned hr = (u + 0x7FFFu + ((u >> 16) & 1u)) >> 16;
    h = (unsigned short)hr;
    float hf = __uint_as_float(hr << 16);
    float r = x - hf;
    unsigned v = __float_as_uint(r);
    l = (unsigned short)((v + 0x7FFFu + ((v >> 16) & 1u)) >> 16);
}

// ---------------------------------------------------------------------------
// Input GEMMs (round-8 proven): 256-thread 128x128 tile.
// MODE 1: A = embed[gidx[m]], +bias; MODE 2: A = relu(embed[gidx[m-1]]), row0=0
// ---------------------------------------------------------------------------
template<int MODE>
__device__ void gemm_body(const float* __restrict__ B, int ldb,
                          const float* __restrict__ bias,
                          float* __restrict__ C, int ldc,
                          const float* __restrict__ embed,
                          const int* __restrict__ gidx,
                          int m0, int n0, int K)
{
    __shared__ float As[16][128];
    __shared__ float Bs[16][128];
    const int tid = threadIdx.x;

    float acc[8][8];
#pragma unroll
    for (int r = 0; r < 8; ++r)
#pragma unroll
        for (int c = 0; c < 8; ++c) acc[r][c] = 0.0f;

    const int ty = tid >> 4;
    const int tx = tid & 15;

    for (int k0 = 0; k0 < K; k0 += 16) {
#pragma unroll
        for (int q = 0; q < 2; ++q) {
            int id = tid * 2 + q;
            int m  = id >> 2;
            int c4 = (id & 3) * 4;
            float4 v;
            if (MODE == 1) {
                int row = gidx[m0 + m];
                v = *(const float4*)(embed + (size_t)row * HDIM + k0 + c4);
            } else {
                int mg = m0 + m;
                if (mg == 0) {
                    v = make_float4(0.f, 0.f, 0.f, 0.f);
                } else {
                    int row = gidx[mg - 1];
                    v = *(const float4*)(embed + (size_t)row * HDIM + k0 + c4);
                    v.x = fmaxf(v.x, 0.f); v.y = fmaxf(v.y, 0.f);
                    v.z = fmaxf(v.z, 0.f); v.w = fmaxf(v.w, 0.f);
                }
            }
            As[c4 + 0][m] = v.x; As[c4 + 1][m] = v.y;
            As[c4 + 2][m] = v.z; As[c4 + 3][m] = v.w;
        }
#pragma unroll
        for (int q = 0; q < 2; ++q) {
            int id = tid * 2 + q;
            int n  = id >> 2;
            int c4 = (id & 3) * 4;
            float4 v = *(const float4*)(B + (size_t)(n0 + n) * ldb + k0 + c4);
            Bs[c4 + 0][n] = v.x; Bs[c4 + 1][n] = v.y;
            Bs[c4 + 2][n] = v.z; Bs[c4 + 3][n] = v.w;
        }
        __syncthreads();
#pragma unroll
        for (int k = 0; k < 16; ++k) {
            float4 a0 = *(const float4*)&As[k][ty * 8];
            float4 a1 = *(const float4*)&As[k][ty * 8 + 4];
            float4 b0 = *(const float4*)&Bs[k][tx * 8];
            float4 b1 = *(const float4*)&Bs[k][tx * 8 + 4];
            float av[8] = {a0.x,a0.y,a0.z,a0.w,a1.x,a1.y,a1.z,a1.w};
            float bv[8] = {b0.x,b0.y,b0.z,b0.w,b1.x,b1.y,b1.z,b1.w};
#pragma unroll
            for (int r = 0; r < 8; ++r)
#pragma unroll
                for (int c = 0; c < 8; ++c)
                    acc[r][c] = fmaf(av[r], bv[c], acc[r][c]);
        }
        __syncthreads();
    }

    const int mbase = m0 + ty * 8;
    const int nbase = n0 + tx * 8;
#pragma unroll
    for (int r = 0; r < 8; ++r) {
        float4 o0, o1;
        float b0 = (MODE == 2) ? 0.f : bias[nbase + 0];
        float b1 = (MODE == 2) ? 0.f : bias[nbase + 1];
        float b2 = (MODE == 2) ? 0.f : bias[nbase + 2];
        float b3 = (MODE == 2) ? 0.f : bias[nbase + 3];
        float b4 = (MODE == 2) ? 0.f : bias[nbase + 4];
        float b5 = (MODE == 2) ? 0.f : bias[nbase + 5];
        float b6 = (MODE == 2) ? 0.f : bias[nbase + 6];
        float b7 = (MODE == 2) ? 0.f : bias[nbase + 7];
        o0.x = acc[r][0] + b0; o0.y = acc[r][1] + b1;
        o0.z = acc[r][2] + b2; o0.w = acc[r][3] + b3;
        o1.x = acc[r][4] + b4; o1.y = acc[r][5] + b5;
        o1.z = acc[r][6] + b6; o1.w = acc[r][7] + b7;
        *(float4*)(C + (size_t)(mbase + r) * ldc + nbase)     = o0;
        *(float4*)(C + (size_t)(mbase + r) * ldc + nbase + 4) = o1;
    }
}

__global__ __launch_bounds__(256)
void g_both(const float* __restrict__ embed,
            const int* __restrict__ input_seq,
            const int* __restrict__ gold_seq,
            const float* __restrict__ enc_Wih,
            const float* __restrict__ enc_b,
            const float* __restrict__ dec_Wih,
            float* __restrict__ G_enc,
            float* __restrict__ G_dec)
{
    const int bx = blockIdx.x, by = blockIdx.y;
    if (by < 8)
        gemm_body<1>(enc_Wih, HDIM, enc_b, G_enc, 4 * HDIM,
                     embed, input_seq, by * 128, bx * 128, HDIM);
    else
        gemm_body<2>(dec_Wih, 2 * HDIM, nullptr, G_dec, 4 * HDIM,
                     embed, gold_seq, (by - 8) * 128, bx * 128, HDIM);
}

// ---------------------------------------------------------------------------
// LSTM body (round-5 proven step) with 2-step G prefetch ring.
// GCTX=0: encoder; GCTX=1: decoder (+gctx per thread).
// ---------------------------------------------------------------------------
#define LSTM_STEP(T, GREG)                                                    \
    {                                                                         \
        const float* hp = ((T) == 0) ? h_init                                 \
                                     : (h_out + (size_t)((T) - 1) * HDIM);    \
        if (wv == 0) {                                                        \
            f4 a, b, cc, d;                                                   \
            const float* p = hp + 4 * lg;                                     \
            for (;;) {                                                        \
                llc_load_4x4(p, a, b, cc, d);                                 \
                if (!__any(any_nan16(a, b, cc, d))) break;                    \
                __builtin_amdgcn_s_sleep(1);                                  \
            }                                                                 \
            hbuf[swz(lg)]       = a;                                          \
            hbuf[swz(64 + lg)]  = b;                                          \
            hbuf[swz(128 + lg)] = cc;                                         \
            hbuf[swz(192 + lg)] = d;                                          \
        }                                                                     \
        __syncthreads();                                                      \
        f4 h0 = hbuf[swz(lg)];                                                \
        f4 h1 = hbuf[swz(64 + lg)];                                           \
        f4 h2 = hbuf[swz(128 + lg)];                                          \
        f4 h3 = hbuf[swz(192 + lg)];                                          \
        float p0 = 0.f, p1 = 0.f, p2 = 0.f, p3 = 0.f;                         \
        f4 hv;                                                                \
        _Pragma("unroll")                                                     \
        for (int i = 0; i < 4; ++i) {                                         \
            hv = (i == 0) ? h0 : (i == 1) ? h1 : (i == 2) ? h2 : h3;          \
            p0 = fmaf(W[0][i].x, hv.x, fmaf(W[0][i].y, hv.y,                  \
                 fmaf(W[0][i].z, hv.z, fmaf(W[0][i].w, hv.w, p0))));          \
            p1 = fmaf(W[1][i].x, hv.x, fmaf(W[1][i].y, hv.y,                  \
                 fmaf(W[1][i].z, hv.z, fmaf(W[1][i].w, hv.w, p1))));          \
            p2 = fmaf(W[2][i].x, hv.x, fmaf(W[2][i].y, hv.y,                  \
                 fmaf(W[2][i].z, hv.z, fmaf(W[2][i].w, hv.w, p2))));          \
            p3 = fmaf(W[3][i].x, hv.x, fmaf(W[3][i].y, hv.y,                  \
                 fmaf(W[3][i].z, hv.z, fmaf(W[3][i].w, hv.w, p3))));          \
        }                                                                     \
        float t01 = __shfl_xor((lg & 1) ? p0 : p1, 1);                        \
        float s01 = ((lg & 1) ? p1 : p0) + t01;                               \
        float t23 = __shfl_xor((lg & 1) ? p2 : p3, 1);                        \
        float s23 = ((lg & 1) ? p3 : p2) + t23;                               \
        float tq  = __shfl_xor((lg & 2) ? s01 : s23, 2);                      \
        float s   = ((lg & 2) ? s23 : s01) + tq;                              \
        s += __shfl_xor(s, 4);                                                \
        s += __shfl_xor(s, 8);                                                \
        s += __shfl_xor(s, 16);                                               \
        s += __shfl_xor(s, 32);                                               \
        float pre = s + (GREG);                                               \
        float act = ((lg & 3) == 2) ? tanhf(pre) : sigmoidf_(pre);            \
        float a1 = __shfl(act, 1);                                            \
        float a2 = __shfl(act, 2);                                            \
        float a3 = __shfl(act, 3);                                            \
        if (lg == 0) {                                                        \
            c = a1 * c + act * a2;                                            \
            float h = a3 * tanhf(c);                                          \
            csum += h;                                                        \
            agent_storef(h_out + (size_t)(T) * HDIM + j, h);                  \
        }                                                                     \
        __syncthreads();                                                      \
    }

template<int GCTX>
__device__ void lstm_body(const float* __restrict__ Whh,
                          const float* __restrict__ G,
                          const float* __restrict__ gctx_vec,
                          const float* __restrict__ h_init,
                          const float* __restrict__ c_init,
                          float* __restrict__ h_out,
                          float* __restrict__ c_fin,
                          float* __restrict__ csum_out,
                          int slen)
{
    __shared__ f4 hbuf[256];
    const int tid = threadIdx.x;
    const int g   = blockIdx.x;
    const int wv  = tid >> 6;
    const int lg  = tid & 63;
    const int j   = g * 8 + wv;

    f4 W[4][4];
#pragma unroll
    for (int q = 0; q < 4; ++q)
#pragma unroll
        for (int i = 0; i < 4; ++i)
            W[q][i] = *(const f4*)(Whh + (size_t)(j + q * HDIM) * HDIM
                                   + 4 * lg + 256 * i);

    float c = 0.0f, csum = 0.0f;
    if (lg == 0) c = c_init[j];

    float gctx = 0.0f;
    if (GCTX) gctx = gctx_vec[(size_t)(lg & 3) * HDIM + j];

    const float* gbase = G + (size_t)(lg & 3) * HDIM + j;
    float gA = gbase[0] + gctx;                        // t = 0
    float gB = gbase[(size_t)4 * HDIM] + gctx;         // t = 1

    for (int t = 0; t < slen; t += 2) {
#pragma unroll
        for (int q = 0; q < 4; ++q)
#pragma unroll
            for (int i = 0; i < 4; ++i)
                asm volatile("" : "+v"(W[q][i]));

        // issue prefetch for t+2, t+3 NOW (no waitcnt) — consumed after two
        // full recurrence steps (~10k cycles of slack; HBM-cold safe).
        int t2 = (t + 2 < slen) ? (t + 2) : (slen - 1);
        int t3 = (t + 3 < slen) ? (t + 3) : (slen - 1);
        const float* pA = gbase + (size_t)t2 * 4 * HDIM;
        const float* pB = gbase + (size_t)t3 * 4 * HDIM;
        float rA, rB;
        asm volatile("global_load_dword %0, %2, off\n\t"
                     "global_load_dword %1, %3, off"
                     : "=&v"(rA), "=&v"(rB)
                     : "v"(pA), "v"(pB));

        LSTM_STEP(t, gA);
        LSTM_STEP(t + 1, gB);

        asm volatile("s_waitcnt vmcnt(0)" ::: "memory");
        __builtin_amdgcn_sched_barrier(0);
        gA = rA + gctx;
        gB = rB + gctx;
    }

    if (lg == 0) {
        if (c_fin)    c_fin[j]    = c;
        if (csum_out) csum_out[j] = csum;
    }
}

__global__ __launch_bounds__(512, 2)
void lstm_seq(const float* __restrict__ Whh, const float* __restrict__ G,
              const float* __restrict__ h_init, const float* __restrict__ c_init,
              float* __restrict__ h_out, float* __restrict__ c_fin,
              float* __restrict__ csum_out, int slen)
{
    lstm_body<0>(Whh, G, nullptr, h_init, c_init, h_out, c_fin, csum_out, slen);
}

__global__ __launch_bounds__(512, 2)
void dec_lstm(const float* __restrict__ Whh, const float* __restrict__ G,
              const float* __restrict__ ctxb, const float* __restrict__ h_init,
              const float* __restrict__ c_init, float* __restrict__ h_out,
              int slen)
{
    lstm_body<1>(Whh, G, ctxb, h_init, c_init, h_out, nullptr, nullptr, slen);
}

// ctx_bias[r] = dec_b[r] + dot(dec_Wih[r, H:2H], context)
__global__ __launch_bounds__(256)
void ctx_bias_k(const float* __restrict__ dec_Wih,
                const float* __restrict__ dec_b,
                const float* __restrict__ ctx,
                float* __restrict__ out)
{
    const int wv = threadIdx.x >> 6;
    const int lane = threadIdx.x & 63;
    const int r = blockIdx.x * 4 + wv;
    const float* wr = dec_Wih + (size_t)r * (2 * HDIM) + HDIM;
    float s = 0.f;
    for (int k = lane; k < HDIM; k += 64) s += wr[k] * ctx[k];
#pragma unroll
    for (int off = 32; off > 0; off >>= 1) s += __shfl_xor(s, off);
    if (lane == 0) out[r] = s + dec_b[r];
}

// ---------------------------------------------------------------------------
// logits_mfma v2: C(1024,32000) = dec_h @ out_w^T + out_b, bf16x3 split
// (ah*bh + ah*bl + al*bh, fp32 MFMA accum), fused per-row argmax.
// Grid (250, 4), 512 threads (8 waves). Tile 256m x 128n, K-chunk 32.
// Wave w: m-block (w>>1)*64, n-block (w&1)*64; 4x4 frags of 16x16x32.
// LDS rows stride 40 ushorts (80B): short8 reads 16B-aligned, ~2-way banks.
// ---------------------------------------------------------------------------
#define LSTR 40

__global__ __launch_bounds__(512, 1)
void logits_mfma(const float* __restrict__ Amat,   // dec_h (S,H)
                 const float* __restrict__ Bmat,   // out_w (V,H)
                 const float* __restrict__ bias,   // out_b (V)
                 float* __restrict__ C,            // (S,V)
                 unsigned long long* __restrict__ amax)
{
    __shared__ unsigned short Ah[256][LSTR], Al[256][LSTR];
    __shared__ unsigned short Bh[128][LSTR], Bl[128][LSTR];

    const int tid = threadIdx.x;
    const int l   = tid & 63;
    const int w   = tid >> 6;
    const int n0  = blockIdx.x * 128;
    const int m0  = blockIdx.y * 256;
    const int mb  = (w >> 1) * 64;
    const int nb  = (w & 1) * 64;

    f32x4 acc[4][4];
#pragma unroll
    for (int i = 0; i < 4; ++i)
#pragma unroll
        for (int jj = 0; jj < 4; ++jj) acc[i][jj] = (f32x4){0.f, 0.f, 0.f, 0.f};

    for (int k0 = 0; k0 < HDIM; k0 += 32) {
        // ---- stage A (256 rows x 32 k): 2048 float4 -> 4 per thread
#pragma unroll
        for (int q = 0; q < 4; ++q) {
            int id  = q * 512 + tid;
            int row = id >> 3;
            int kq  = (id & 7) * 4;
            float4 av = *(const float4*)(Amat + (size_t)(m0 + row) * HDIM
                                         + k0 + kq);
            unsigned short h0,h1,h2,h3, l0,l1,l2,l3;
            split_bf16(av.x, h0, l0); split_bf16(av.y, h1, l1);
            split_bf16(av.z, h2, l2); split_bf16(av.w, h3, l3);
            sh4 hi = {(short)h0, (short)h1, (short)h2, (short)h3};
            sh4 lo = {(short)l0, (short)l1, (short)l2, (short)l3};
            *(sh4*)&Ah[row][kq] = hi;
            *(sh4*)&Al[row][kq] = lo;
        }
        // ---- stage B (128 rows x 32 k): 1024 float4 -> 2 per thread
#pragma unroll
        for (int q = 0; q < 2; ++q) {
            int id  = q * 512 + tid;
            int row = id >> 3;
            int kq  = (id & 7) * 4;
            float4 bv = *(const float4*)(Bmat + (size_t)(n0 + row) * HDIM
                                         + k0 + kq);
            unsigned short h0,h1,h2,h3, l0,l1,l2,l3;
            split_bf16(bv.x, h0, l0); split_bf16(bv.y, h1, l1);
            split_bf16(bv.z, h2, l2); split_bf16(bv.w, h3, l3);
            sh4 hi = {(short)h0, (short)h1, (short)h2, (short)h3};
            sh4 lo = {(short)l0, (short)l1, (short)l2, (short)l3};
            *(sh4*)&Bh[row][kq] = hi;
            *(sh4*)&Bl[row][kq] = lo;
        }
        __syncthreads();

        const int kb = (l >> 4) * 8;
        short8 a_hi[4], a_lo[4], b_hi[4], b_lo[4];
#pragma unroll
        for (int i = 0; i < 4; ++i) {
            int ra = mb + i * 16 + (l & 15);
            int rb = nb + i * 16 + (l & 15);
            a_hi[i] = *(const short8*)&Ah[ra][kb];
            a_lo[i] = *(const short8*)&Al[ra][kb];
            b_hi[i] = *(const short8*)&Bh[rb][kb];
            b_lo[i] = *(const short8*)&Bl[rb][kb];
        }
#pragma unroll
        for (int i = 0; i < 4; ++i)
#pragma unroll
            for (int jj = 0; jj < 4; ++jj) {
                acc[i][jj] = __builtin_amdgcn_mfma_f32_16x16x32_bf16(
                    a_hi[i], b_hi[jj], acc[i][jj], 0, 0, 0);
                acc[i][jj] = __builtin_amdgcn_mfma_f32_16x16x32_bf16(
                    a_hi[i], b_lo[jj], acc[i][jj], 0, 0, 0);
                acc[i][jj] = __builtin_amdgcn_mfma_f32_16x16x32_bf16(
                    a_lo[i], b_hi[jj], acc[i][jj], 0, 0, 0);
            }
        __syncthreads();
    }

    // epilogue: bias, store, fused argmax (packed monotone-float | ~col key)
#pragma unroll
    for (int i = 0; i < 4; ++i) {
        const int mrow = m0 + mb + i * 16 + ((l >> 4) << 2);
        unsigned long long key[4] = {0ull, 0ull, 0ull, 0ull};
#pragma unroll
        for (int jj = 0; jj < 4; ++jj) {
            int n = n0 + nb + jj * 16 + (l & 15);
            float bv = bias[n];
            f32x4 o = acc[i][jj];
#pragma unroll
            for (int r = 0; r < 4; ++r) {
                float val = o[r] + bv;
                C[(size_t)(mrow + r) * VDIM + n] = val;
                unsigned um = __float_as_uint(val);
                um = (um & 0x80000000u) ? ~um : (um | 0x80000000u);
                unsigned long long k2 = ((unsigned long long)um << 32)
                    | (unsigned long long)(0xFFFFFFFFu - (unsigned)n);
                if (k2 > key[r]) key[r] = k2;
            }
        }
#pragma unroll
        for (int r = 0; r < 4; ++r) {
#pragma unroll
            for (int off = 1; off < 16; off <<= 1) {
                unsigned long long other = __shfl_xor(key[r], off);
                if (other > key[r]) key[r] = other;
            }
            if ((l & 15) == 0)
                atomicMax(&amax[mrow + r], key[r]);
        }
    }
}

// decode argmax keys -> float indices
__global__ __launch_bounds__(256)
void idx_final(const unsigned long long* __restrict__ amax,
               float* __restrict__ out_idx)
{
    int i = blockIdx.x * 256 + threadIdx.x;
    if (i < S_LEN) {
        unsigned col = 0xFFFFFFFFu - (unsigned)(amax[i] & 0xFFFFFFFFull);
        out_idx[i] = (float)col;
    }
}

extern "C" void kernel_launch(void* const* d_in, const int* in_sizes, int n_in,
                              void* d_out, int out_size, void* d_ws, size_t ws_size,
                              hipStream_t stream)
{
    (void)in_sizes; (void)n_in; (void)out_size; (void)ws_size;

    const int*   input_seq = (const int*)d_in[0];
    const int*   gold_seq  = (const int*)d_in[1];
    const float* embed     = (const float*)d_in[2];
    const float* enc_Wih   = (const float*)d_in[3];
    const float* enc_Whh   = (const float*)d_in[4];
    const float* enc_b     = (const float*)d_in[5];
    const float* dec_Wih   = (const float*)d_in[6];
    const float* dec_Whh   = (const float*)d_in[7];
    const float* dec_b     = (const float*)d_in[8];
    // d_in[9..14]: attention params — dead code
    const float* out_w     = (const float*)d_in[15];
    const float* out_b     = (const float*)d_in[16];

    float* out = (float*)d_out;
    float* G_enc = out;                 // dead before logits overwrite (serial)
    float* G_dec = out + 4194304;       // dead before logits overwrite (serial)

    // workspace
    char* wsb = (char*)d_ws;
    unsigned long long* amax = (unsigned long long*)wsb;   // 8 KB
    float* zerovec = (float*)(wsb + 8192);                 // 1024 f
    float* c0      = zerovec + 1024;
    float* ctx     = c0 + 1024;
    float* ctxb    = ctx + 1024;                           // 4096 f
    float* enc_out = ctxb + 4096;                          // S*H
    float* dec_h   = enc_out + 1048576;                    // S*H

    hipMemsetAsync(d_ws, 0, 12288, stream);                // amax + zerovec
    hipMemsetAsync(enc_out, 0xFF, (size_t)S_LEN * HDIM * 4, stream);
    hipMemsetAsync(dec_h,   0xFF, (size_t)S_LEN * HDIM * 4, stream);

    // both input GEMMs, one launch
    g_both<<<dim3(32, 16), 256, 0, stream>>>(
        embed, input_seq, gold_seq, enc_Wih, enc_b, dec_Wih, G_enc, G_dec);

    // encoder
    lstm_seq<<<128, 512, 0, stream>>>(
        enc_Whh, G_enc, zerovec, zerovec, enc_out, c0, ctx, S_LEN);

    // ctxb = dec_b + dec_Wih[:,H:] @ ctx
    ctx_bias_k<<<1024, 256, 0, stream>>>(dec_Wih, dec_b, ctx, ctxb);

    // decoder
    dec_lstm<<<128, 512, 0, stream>>>(
        dec_Whh, G_dec, ctxb, enc_out + (size_t)(S_LEN - 1) * HDIM, c0,
        dec_h, S_LEN);

    // logits (bf16x3 MFMA v2) + fused argmax
    logits_mfma<<<dim3(VDIM / 128, S_LEN / 256), 512, 0, stream>>>(
        dec_h, out_w, out_b, out, amax);

    // idxs -> d_out[S*V : S*V + S)
    idx_final<<<4, 256, 0, stream>>>(amax, out + (size_t)S_LEN * VDIM);
}